// Round 1
// baseline (5033.737 us; speedup 1.0000x reference)
//
#include <hip/hip_runtime.h>
#include <math.h>

#define BB 4
#define CC 256
#define HH 64
#define WW 64
#define NN 4096   // H*W
#define C8 32     // C/8

// ---------------------------------------------------------------------------
// conv 7x7, pad 3, dil 1.  grid = B(4) * ytile(16) * cotile(32) = 2048 blocks,
// 256 threads = 4 rows x 64 cols; each block computes 8 output channels.
// ---------------------------------------------------------------------------
__global__ __launch_bounds__(256) void conv7_kernel(
    const float* __restrict__ x, const float* __restrict__ w,
    const float* __restrict__ bias, float* __restrict__ out)
{
  __shared__ float xs[10][72];   // rows y0-3..y0+6, cols padded +3 halo each side
  int blk = blockIdx.x;
  int cotile = blk & 31;
  int ytile  = (blk >> 5) & 15;
  int b      = blk >> 9;
  int y0  = ytile * 4;
  int co0 = cotile * 8;
  int tid = threadIdx.x;
  int tx = tid & 63;
  int ty = tid >> 6;

  // zero once: halo columns / out-of-range rows stay 0 forever
  for (int i = tid; i < 10*72; i += 256) ((float*)xs)[i] = 0.0f;

  float acc[8];
  #pragma unroll
  for (int j = 0; j < 8; ++j) acc[j] = bias[co0 + j];

  const float* xb = x + (size_t)b * CC * NN;

  for (int ci = 0; ci < CC; ++ci) {
    __syncthreads();   // previous compute done reading xs
    const float* xc = xb + (size_t)ci * NN;
    for (int idx = tid; idx < 640; idx += 256) {   // 10 rows * 64 cols
      int r = idx >> 6, cc2 = idx & 63;
      int yy = y0 - 3 + r;
      if (yy >= 0 && yy < HH) xs[r][cc2 + 3] = xc[yy * WW + cc2];
    }
    __syncthreads();
    const float* wci = w + ((size_t)co0 * CC + ci) * 49;
    #pragma unroll
    for (int kh = 0; kh < 7; ++kh) {
      #pragma unroll
      for (int kw = 0; kw < 7; ++kw) {
        float xv = xs[ty + kh][tx + kw];
        #pragma unroll
        for (int j = 0; j < 8; ++j)
          acc[j] = fmaf(xv, wci[(size_t)j * CC * 49 + kh * 7 + kw], acc[j]);
      }
    }
  }
  int y = y0 + ty;
  size_t obase = (size_t)b * CC * NN + (size_t)y * WW + tx;
  #pragma unroll
  for (int j = 0; j < 8; ++j)
    out[obase + (size_t)(co0 + j) * NN] = acc[j];
}

// ---------------------------------------------------------------------------
// conv 5x5, pad 6, dilation 3.  Same decomposition as conv7.
// tap offset = (k-2)*3 in [-6,6].
// ---------------------------------------------------------------------------
__global__ __launch_bounds__(256) void conv5_kernel(
    const float* __restrict__ x, const float* __restrict__ w,
    const float* __restrict__ bias, float* __restrict__ out)
{
  __shared__ float xs[16][80];   // rows y0-6..y0+9, cols padded +6 halo
  int blk = blockIdx.x;
  int cotile = blk & 31;
  int ytile  = (blk >> 5) & 15;
  int b      = blk >> 9;
  int y0  = ytile * 4;
  int co0 = cotile * 8;
  int tid = threadIdx.x;
  int tx = tid & 63;
  int ty = tid >> 6;

  for (int i = tid; i < 16*80; i += 256) ((float*)xs)[i] = 0.0f;

  float acc[8];
  #pragma unroll
  for (int j = 0; j < 8; ++j) acc[j] = bias[co0 + j];

  const float* xb = x + (size_t)b * CC * NN;

  for (int ci = 0; ci < CC; ++ci) {
    __syncthreads();
    const float* xc = xb + (size_t)ci * NN;
    for (int idx = tid; idx < 1024; idx += 256) {  // 16 rows * 64 cols
      int r = idx >> 6, cc2 = idx & 63;
      int yy = y0 - 6 + r;
      if (yy >= 0 && yy < HH) xs[r][cc2 + 6] = xc[yy * WW + cc2];
    }
    __syncthreads();
    const float* wci = w + ((size_t)co0 * CC + ci) * 25;
    #pragma unroll
    for (int kh = 0; kh < 5; ++kh) {
      #pragma unroll
      for (int kw = 0; kw < 5; ++kw) {
        float xv = xs[ty + 3*kh][tx + 3*kw];
        #pragma unroll
        for (int j = 0; j < 8; ++j)
          acc[j] = fmaf(xv, wci[(size_t)j * CC * 25 + kh * 5 + kw], acc[j]);
      }
    }
  }
  int y = y0 + ty;
  size_t obase = (size_t)b * CC * NN + (size_t)y * WW + tx;
  #pragma unroll
  for (int j = 0; j < 8; ++j)
    out[obase + (size_t)(co0 + j) * NN] = acc[j];
}

// ---------------------------------------------------------------------------
// combine: multi[b,o,n] = b_comb[o] + sum_m wc[o,m]*local + wc[o,256+m]*wide
// grid = (b*256 + o)*16 + ytile = 16384 blocks, 256 threads (4 rows x 64)
// ---------------------------------------------------------------------------
__global__ __launch_bounds__(256) void combine_kernel(
    const float* __restrict__ lo, const float* __restrict__ wi,
    const float* __restrict__ wc, const float* __restrict__ bc,
    float* __restrict__ multi)
{
  int blk = blockIdx.x;
  int ytile = blk & 15;
  int o = (blk >> 4) & 255;
  int b = blk >> 12;
  int tid = threadIdx.x;
  int tx = tid & 63, ty = tid >> 6;
  int n = (ytile * 4 + ty) * WW + tx;
  const float* lp = lo + (size_t)b * CC * NN + n;
  const float* wp = wi + (size_t)b * CC * NN + n;
  const float* wr = wc + (size_t)o * 2 * CC;
  float acc = bc[o];
  for (int mch = 0; mch < CC; ++mch) {
    acc = fmaf(lp[(size_t)mch * NN], wr[mch], acc);
    acc = fmaf(wp[(size_t)mch * NN], wr[CC + mch], acc);
  }
  multi[((size_t)b * CC + o) * NN + n] = acc;
}

// ---------------------------------------------------------------------------
// generic 1x1 conv: out[b,o,n] = bias[o] + sum_m w[o,m]*in[b,m,n]
// grid = (b*Cout + o)*16 + ytile blocks, 256 threads
// ---------------------------------------------------------------------------
__global__ __launch_bounds__(256) void conv1x1_kernel(
    const float* __restrict__ in, const float* __restrict__ w,
    const float* __restrict__ bias, float* __restrict__ out, int Cout)
{
  int blk = blockIdx.x;
  int ytile = blk & 15;
  int rest = blk >> 4;
  int o = rest % Cout;
  int b = rest / Cout;
  int tid = threadIdx.x;
  int tx = tid & 63, ty = tid >> 6;
  int n = (ytile * 4 + ty) * WW + tx;
  const float* ip = in + (size_t)b * CC * NN + n;
  const float* wr = w + (size_t)o * CC;
  float acc = bias[o];
  for (int mch = 0; mch < CC; ++mch)
    acc = fmaf(ip[(size_t)mch * NN], wr[mch], acc);
  out[((size_t)b * Cout + o) * NN + n] = acc;
}

// ---------------------------------------------------------------------------
// transpose v [B][256][4096] -> v_t [B][4096][256]
// grid = B * ctile(8) * ntile(128) = 4096 blocks, 256 threads, 32x32 tiles
// ---------------------------------------------------------------------------
__global__ __launch_bounds__(256) void transpose_kernel(
    const float* __restrict__ v, float* __restrict__ vt)
{
  __shared__ float t[32][33];
  int blk = blockIdx.x;
  int ntile = blk & 127;
  int ctile = (blk >> 7) & 7;
  int b = blk >> 10;
  int c0 = ctile * 32, n0 = ntile * 32;
  int col = threadIdx.x & 31;
  int row = threadIdx.x >> 5;   // 0..7
  #pragma unroll
  for (int i = 0; i < 4; ++i) {
    int r = row + i * 8;
    t[r][col] = v[((size_t)b * CC + c0 + r) * NN + n0 + col];
  }
  __syncthreads();
  #pragma unroll
  for (int i = 0; i < 4; ++i) {
    int r = row + i * 8;
    vt[((size_t)b * NN + n0 + r) * CC + c0 + col] = t[col][r];
  }
}

// ---------------------------------------------------------------------------
// pass A: per (b,m) row of scores: rowmax and sum(exp(s-rowmax))
// grid = B*N = 16384 blocks, 256 threads; each thread handles 16 n strided
// ---------------------------------------------------------------------------
__global__ __launch_bounds__(256) void softmax_stats_kernel(
    const float* __restrict__ q, const float* __restrict__ k,
    float* __restrict__ rowmax, float* __restrict__ rowsum)
{
  int blk = blockIdx.x;
  int m = blk & (NN - 1);
  int b = blk >> 12;
  int tid = threadIdx.x;

  __shared__ float qs[C8];
  __shared__ float redm[4], reds[4];

  if (tid < C8) qs[tid] = q[((size_t)b * C8 + tid) * NN + m];
  __syncthreads();

  const float* kb = k + (size_t)b * C8 * NN;
  float s[16];
  float mymax = -1e30f;
  #pragma unroll
  for (int i = 0; i < 16; ++i) {
    int n = tid + i * 256;
    float acc = 0.f;
    #pragma unroll
    for (int c = 0; c < C8; ++c)
      acc = fmaf(qs[c], kb[(size_t)c * NN + n], acc);
    s[i] = acc;
    mymax = fmaxf(mymax, acc);
  }
  #pragma unroll
  for (int off = 32; off > 0; off >>= 1)
    mymax = fmaxf(mymax, __shfl_xor(mymax, off));
  if ((tid & 63) == 0) redm[tid >> 6] = mymax;
  __syncthreads();
  float rmax = fmaxf(fmaxf(redm[0], redm[1]), fmaxf(redm[2], redm[3]));

  float mysum = 0.f;
  #pragma unroll
  for (int i = 0; i < 16; ++i) mysum += __expf(s[i] - rmax);
  #pragma unroll
  for (int off = 32; off > 0; off >>= 1)
    mysum += __shfl_xor(mysum, off);
  if ((tid & 63) == 0) reds[tid >> 6] = mysum;
  __syncthreads();
  if (tid == 0) {
    rowmax[blk] = rmax;
    rowsum[blk] = reds[0] + reds[1] + reds[2] + reds[3];
  }
}

// ---------------------------------------------------------------------------
// pass B: out[b,c,m] = (1+mask_r) * sum_n softmax(s)[m,n] * v[c,n]
// grid = B * (N/16) = 1024 blocks, 256 threads. Thread owns channel c=tid,
// accumulates 16 m-rows. Scores recomputed per 256-col chunk.
// ---------------------------------------------------------------------------
__global__ __launch_bounds__(256) void attn_out_kernel(
    const float* __restrict__ q, const float* __restrict__ k,
    const float* __restrict__ vt, const float* __restrict__ rowmax,
    const float* __restrict__ rowsum, const float* __restrict__ mask,
    float* __restrict__ out)
{
  int blk = blockIdx.x;
  int mt = blk & 255;
  int b = blk >> 8;
  int m0 = mt * 16;
  int tid = threadIdx.x;

  __shared__ float qs[C8][16];
  __shared__ float ps[256][20];         // stride 20 floats: conflict-free writes
  __shared__ float rmax_s[16], rsuminv_s[16];

  for (int idx = tid; idx < C8 * 16; idx += 256) {
    int c = idx >> 4, mi = idx & 15;
    qs[c][mi] = q[((size_t)b * C8 + c) * NN + m0 + mi];
  }
  if (tid < 16) {
    rmax_s[tid] = rowmax[(size_t)b * NN + m0 + tid];
    rsuminv_s[tid] = 1.0f / rowsum[(size_t)b * NN + m0 + tid];
  }
  __syncthreads();

  float acc[16];
  #pragma unroll
  for (int i = 0; i < 16; ++i) acc[i] = 0.f;

  const float* kb = k + (size_t)b * C8 * NN;
  const float* vb = vt + (size_t)b * NN * CC;

  for (int n0 = 0; n0 < NN; n0 += 256) {
    // score column n0+tid for all 16 m rows
    float s[16];
    #pragma unroll
    for (int i = 0; i < 16; ++i) s[i] = 0.f;
    for (int c = 0; c < C8; ++c) {
      float kv = kb[(size_t)c * NN + n0 + tid];
      #pragma unroll
      for (int mi = 0; mi < 16; ++mi)
        s[mi] = fmaf(kv, qs[c][mi], s[mi]);
    }
    __syncthreads();   // previous accum phase done reading ps
    #pragma unroll
    for (int mi = 0; mi < 16; ++mi)
      ps[tid][mi] = __expf(s[mi] - rmax_s[mi]) * rsuminv_s[mi];
    __syncthreads();
    // accumulate: thread owns channel c = tid
    for (int nj = 0; nj < 256; ++nj) {
      float vv = vb[(size_t)(n0 + nj) * CC + tid];
      #pragma unroll
      for (int mi = 0; mi < 16; ++mi)
        acc[mi] = fmaf(vv, ps[nj][mi], acc[mi]);
    }
  }

  // epilogue: multiply by (1 + mask[b,0,4y,4x]), write out[b,c,m]
  int y = m0 >> 6;
  int x0 = m0 & 63;
  const float* mb = mask + (size_t)b * 256 * 256;
  size_t ob = ((size_t)b * CC + tid) * NN + m0;
  #pragma unroll
  for (int mi = 0; mi < 16; ++mi) {
    float mv = mb[(4 * y) * 256 + 4 * (x0 + mi)];
    out[ob + mi] = acc[mi] * (1.0f + mv);
  }
}

// ---------------------------------------------------------------------------
extern "C" void kernel_launch(void* const* d_in, const int* in_sizes, int n_in,
                              void* d_out, int out_size, void* d_ws, size_t ws_size,
                              hipStream_t stream)
{
  (void)in_sizes; (void)n_in; (void)out_size; (void)ws_size;
  const float* x      = (const float*)d_in[0];
  const float* mask   = (const float*)d_in[1];
  const float* w_ctx  = (const float*)d_in[2];
  const float* b_ctx  = (const float*)d_in[3];
  const float* w_wide = (const float*)d_in[4];
  const float* b_wide = (const float*)d_in[5];
  const float* w_comb = (const float*)d_in[6];
  const float* b_comb = (const float*)d_in[7];
  const float* w_q    = (const float*)d_in[8];
  const float* b_q    = (const float*)d_in[9];
  const float* w_k    = (const float*)d_in[10];
  const float* b_k    = (const float*)d_in[11];
  const float* w_v    = (const float*)d_in[12];
  const float* b_v    = (const float*)d_in[13];
  float* out = (float*)d_out;

  float* ws = (float*)d_ws;
  const size_t SZ = (size_t)BB * CC * NN;            // 4,194,304 floats
  float* local  = ws;                                // reused for v after combine
  float* wide   = ws + SZ;                           // reused for v_t
  float* multi  = ws + 2 * SZ;
  float* qbuf   = ws + 3 * SZ;                       // B*32*N
  float* kbuf   = qbuf + (size_t)BB * C8 * NN;
  float* rowmax = kbuf + (size_t)BB * C8 * NN;
  float* rowsum = rowmax + (size_t)BB * NN;
  // total ~54.7 MB

  conv7_kernel<<<2048, 256, 0, stream>>>(x, w_ctx, b_ctx, local);
  conv5_kernel<<<2048, 256, 0, stream>>>(x, w_wide, b_wide, wide);
  combine_kernel<<<16384, 256, 0, stream>>>(local, wide, w_comb, b_comb, multi);
  conv1x1_kernel<<<2048, 256, 0, stream>>>(multi, w_q, b_q, qbuf, 32);
  conv1x1_kernel<<<2048, 256, 0, stream>>>(multi, w_k, b_k, kbuf, 32);
  conv1x1_kernel<<<16384, 256, 0, stream>>>(multi, w_v, b_v, local, 256);   // v
  transpose_kernel<<<4096, 256, 0, stream>>>(local, wide);                  // v_t
  softmax_stats_kernel<<<16384, 256, 0, stream>>>(qbuf, kbuf, rowmax, rowsum);
  attn_out_kernel<<<1024, 256, 0, stream>>>(qbuf, kbuf, wide, rowmax, rowsum,
                                            mask, out);
}

// Round 2
// 1687.662 us; speedup vs baseline: 2.9827x; 2.9827x over previous
//
#include <hip/hip_runtime.h>
#include <math.h>

#define BB 4
#define CC 256
#define HH 64
#define WW 64
#define NN 4096   // H*W
#define C8 32     // C/8

typedef _Float16 f16x8 __attribute__((ext_vector_type(8)));
typedef float f32x4 __attribute__((ext_vector_type(4)));

// ---------------------------------------------------------------------------
// pad + transpose: xpad[b][pr][pc][ci] = x[b][ci][pr-6][pc-6]  (f16, 0-padded)
// grid = B*76 blocks, 256 threads (ci)
// ---------------------------------------------------------------------------
__global__ __launch_bounds__(256) void pad_kernel(
    const float* __restrict__ x, _Float16* __restrict__ xpad)
{
  int blk = blockIdx.x;
  int pr = blk % 76;
  int b  = blk / 76;
  int ci = threadIdx.x;
  int r = pr - 6;
  _Float16* dst = xpad + (((size_t)b*76 + pr)*76)*256 + ci;
  if (r < 0 || r >= HH) {
    for (int pc = 0; pc < 76; ++pc) dst[(size_t)pc*256] = (_Float16)0.f;
  } else {
    const float* src = x + ((size_t)b*CC + ci)*NN + (size_t)r*WW;
    for (int pc = 0; pc < 76; ++pc) {
      int c = pc - 6;
      float v = (c >= 0 && c < WW) ? src[c] : 0.f;
      dst[(size_t)pc*256] = (_Float16)v;
    }
  }
}

// ---------------------------------------------------------------------------
// weight convert: dst[t][co][ci] = (f16) src[co][ci][t];  t < T (49 or 25)
// grid = 256 blocks (co), 256 threads (ci)
// ---------------------------------------------------------------------------
__global__ __launch_bounds__(256) void wcvt_kernel(
    const float* __restrict__ src, _Float16* __restrict__ dst, int T)
{
  int co = blockIdx.x;
  int ci = threadIdx.x;
  const float* s = src + ((size_t)co*256 + ci)*T;
  for (int t = 0; t < T; ++t)
    dst[(size_t)t*65536 + co*256 + ci] = (_Float16)s[t];
}

// ---------------------------------------------------------------------------
// implicit-GEMM conv via MFMA 16x16x32 f16.
// grid = B(4) * cot(2) * ytile(32) = 256 blocks, 512 threads = 8 waves.
// block tile: co 128 x spatial (2 rows x 64 cols). wave tile: 32co x 64sp.
// A (weights) read direct from global (L1-shared); B (x) LDS-staged per kh,
// XOR-swizzled to avoid stride-512B bank conflicts on ds_read_b128.
// ---------------------------------------------------------------------------
template<int KS, int DIL>
__global__ __launch_bounds__(512) void conv_mfma_kernel(
    const _Float16* __restrict__ xpad, const _Float16* __restrict__ wb,
    const float* __restrict__ bias, _Float16* __restrict__ out)
{
  __shared__ __align__(16) char xs[2*76*512];   // [2 rows][76 cols][256 ci] f16

  int blk = blockIdx.x;
  int ytile = blk & 31;
  int cot = (blk >> 5) & 1;
  int b = blk >> 6;
  int y0 = ytile * 2;
  int tid = threadIdx.x;
  int lane = tid & 63;
  int wv = tid >> 6;
  int wco = wv >> 1;           // 0..3  -> co strip of 32
  int wsp = wv & 1;            // row y0+wsp
  int l15 = lane & 15;
  int lg  = lane >> 4;

  f32x4 acc[2][4];
  #pragma unroll
  for (int m = 0; m < 2; ++m)
    #pragma unroll
    for (int n = 0; n < 4; ++n) acc[m][n] = (f32x4){0.f, 0.f, 0.f, 0.f};

  for (int kh = 0; kh < KS; ++kh) {
    int prow = 6 + y0 + (kh - KS/2) * DIL;
    const uint4* src = (const uint4*)(xpad + (((size_t)b*76 + prow)*76)*256);
    __syncthreads();
    #pragma unroll
    for (int i = 0; i < 10; ++i) {
      int ch = tid + i*512;               // 16B chunks; 2 rows = 4864 chunks
      if (ch < 4864) {
        uint4 v = src[ch];
        int r = ch >> 5, cq = ch & 31;    // r: 512B LDS row, cq: chunk in row
        *(uint4*)(xs + r*512 + ((cq << 4) ^ ((r & 7) << 4))) = v;
      }
    }
    __syncthreads();
    for (int kw = 0; kw < KS; ++kw) {
      int dx = (kw - KS/2) * DIL;
      int tap = kh*KS + kw;
      const _Float16* wt = wb + ((size_t)tap << 16)
                              + ((size_t)(cot*128 + wco*32 + l15) << 8) + (lg << 3);
      #pragma unroll
      for (int ks = 0; ks < 8; ++ks) {
        f16x8 a0 = *(const f16x8*)(wt + ks*32);
        f16x8 a1 = *(const f16x8*)(wt + 16*256 + ks*32);
        #pragma unroll
        for (int nf = 0; nf < 4; ++nf) {
          int r = wsp*76 + 6 + nf*16 + l15 + dx;
          f16x8 bf = *(const f16x8*)(xs + r*512 + ((ks*64 + (lg << 4)) ^ ((r & 7) << 4)));
          acc[0][nf] = __builtin_amdgcn_mfma_f32_16x16x32_f16(a0, bf, acc[0][nf], 0, 0, 0);
          acc[1][nf] = __builtin_amdgcn_mfma_f32_16x16x32_f16(a1, bf, acc[1][nf], 0, 0, 0);
        }
      }
    }
  }

  // epilogue: C/D layout col=lane&15 (x), row=(lane>>4)*4+i (co within frag)
  int y = y0 + wsp;
  #pragma unroll
  for (int m = 0; m < 2; ++m) {
    #pragma unroll
    for (int i = 0; i < 4; ++i) {
      int co = cot*128 + wco*32 + m*16 + lg*4 + i;
      float bs = bias[co];
      _Float16* op = out + ((size_t)b*CC + co)*NN + (size_t)y*WW;
      #pragma unroll
      for (int nf = 0; nf < 4; ++nf)
        op[nf*16 + l15] = (_Float16)(acc[m][nf][i] + bs);
    }
  }
}

// ---------------------------------------------------------------------------
// combine: multi[b,o,n] = b_comb[o] + sum_m wc[o,m]*local(f16) + wc[o,256+m]*wide(f16)
// ---------------------------------------------------------------------------
__global__ __launch_bounds__(256) void combine_kernel(
    const _Float16* __restrict__ lo, const _Float16* __restrict__ wi,
    const float* __restrict__ wc, const float* __restrict__ bc,
    float* __restrict__ multi)
{
  int blk = blockIdx.x;
  int ytile = blk & 15;
  int o = (blk >> 4) & 255;
  int b = blk >> 12;
  int tid = threadIdx.x;
  int tx = tid & 63, ty = tid >> 6;
  int n = (ytile * 4 + ty) * WW + tx;
  const _Float16* lp = lo + (size_t)b * CC * NN + n;
  const _Float16* wp = wi + (size_t)b * CC * NN + n;
  const float* wr = wc + (size_t)o * 2 * CC;
  float acc = bc[o];
  for (int mch = 0; mch < CC; ++mch) {
    acc = fmaf((float)lp[(size_t)mch * NN], wr[mch], acc);
    acc = fmaf((float)wp[(size_t)mch * NN], wr[CC + mch], acc);
  }
  multi[((size_t)b * CC + o) * NN + n] = acc;
}

// ---------------------------------------------------------------------------
// generic 1x1 conv (fp32): out[b,o,n] = bias[o] + sum_m w[o,m]*in[b,m,n]
// ---------------------------------------------------------------------------
__global__ __launch_bounds__(256) void conv1x1_kernel(
    const float* __restrict__ in, const float* __restrict__ w,
    const float* __restrict__ bias, float* __restrict__ out, int Cout)
{
  int blk = blockIdx.x;
  int ytile = blk & 15;
  int rest = blk >> 4;
  int o = rest % Cout;
  int b = rest / Cout;
  int tid = threadIdx.x;
  int tx = tid & 63, ty = tid >> 6;
  int n = (ytile * 4 + ty) * WW + tx;
  const float* ip = in + (size_t)b * CC * NN + n;
  const float* wr = w + (size_t)o * CC;
  float acc = bias[o];
  for (int mch = 0; mch < CC; ++mch)
    acc = fmaf(ip[(size_t)mch * NN], wr[mch], acc);
  out[((size_t)b * Cout + o) * NN + n] = acc;
}

// ---------------------------------------------------------------------------
// transpose v [B][256][4096] -> v_t [B][4096][256]
// ---------------------------------------------------------------------------
__global__ __launch_bounds__(256) void transpose_kernel(
    const float* __restrict__ v, float* __restrict__ vt)
{
  __shared__ float t[32][33];
  int blk = blockIdx.x;
  int ntile = blk & 127;
  int ctile = (blk >> 7) & 7;
  int b = blk >> 10;
  int c0 = ctile * 32, n0 = ntile * 32;
  int col = threadIdx.x & 31;
  int row = threadIdx.x >> 5;   // 0..7
  #pragma unroll
  for (int i = 0; i < 4; ++i) {
    int r = row + i * 8;
    t[r][col] = v[((size_t)b * CC + c0 + r) * NN + n0 + col];
  }
  __syncthreads();
  #pragma unroll
  for (int i = 0; i < 4; ++i) {
    int r = row + i * 8;
    vt[((size_t)b * NN + n0 + r) * CC + c0 + col] = t[col][r];
  }
}

// ---------------------------------------------------------------------------
// pass A: per (b,m) row of scores: rowmax and sum(exp(s-rowmax))
// ---------------------------------------------------------------------------
__global__ __launch_bounds__(256) void softmax_stats_kernel(
    const float* __restrict__ q, const float* __restrict__ k,
    float* __restrict__ rowmax, float* __restrict__ rowsum)
{
  int blk = blockIdx.x;
  int m = blk & (NN - 1);
  int b = blk >> 12;
  int tid = threadIdx.x;

  __shared__ float qs[C8];
  __shared__ float redm[4], reds[4];

  if (tid < C8) qs[tid] = q[((size_t)b * C8 + tid) * NN + m];
  __syncthreads();

  const float* kb = k + (size_t)b * C8 * NN;
  float s[16];
  float mymax = -1e30f;
  #pragma unroll
  for (int i = 0; i < 16; ++i) {
    int n = tid + i * 256;
    float acc = 0.f;
    #pragma unroll
    for (int c = 0; c < C8; ++c)
      acc = fmaf(qs[c], kb[(size_t)c * NN + n], acc);
    s[i] = acc;
    mymax = fmaxf(mymax, acc);
  }
  #pragma unroll
  for (int off = 32; off > 0; off >>= 1)
    mymax = fmaxf(mymax, __shfl_xor(mymax, off));
  if ((tid & 63) == 0) redm[tid >> 6] = mymax;
  __syncthreads();
  float rmax = fmaxf(fmaxf(redm[0], redm[1]), fmaxf(redm[2], redm[3]));

  float mysum = 0.f;
  #pragma unroll
  for (int i = 0; i < 16; ++i) mysum += __expf(s[i] - rmax);
  #pragma unroll
  for (int off = 32; off > 0; off >>= 1)
    mysum += __shfl_xor(mysum, off);
  if ((tid & 63) == 0) reds[tid >> 6] = mysum;
  __syncthreads();
  if (tid == 0) {
    rowmax[blk] = rmax;
    rowsum[blk] = reds[0] + reds[1] + reds[2] + reds[3];
  }
}

// ---------------------------------------------------------------------------
// pass B: out[b,c,m] = (1+mask_r) * sum_n softmax(s)[m,n] * v[c,n]
// ---------------------------------------------------------------------------
__global__ __launch_bounds__(256) void attn_out_kernel(
    const float* __restrict__ q, const float* __restrict__ k,
    const float* __restrict__ vt, const float* __restrict__ rowmax,
    const float* __restrict__ rowsum, const float* __restrict__ mask,
    float* __restrict__ out)
{
  int blk = blockIdx.x;
  int mt = blk & 255;
  int b = blk >> 8;
  int m0 = mt * 16;
  int tid = threadIdx.x;

  __shared__ float qs[C8][16];
  __shared__ float ps[256][20];
  __shared__ float rmax_s[16], rsuminv_s[16];

  for (int idx = tid; idx < C8 * 16; idx += 256) {
    int c = idx >> 4, mi = idx & 15;
    qs[c][mi] = q[((size_t)b * C8 + c) * NN + m0 + mi];
  }
  if (tid < 16) {
    rmax_s[tid] = rowmax[(size_t)b * NN + m0 + tid];
    rsuminv_s[tid] = 1.0f / rowsum[(size_t)b * NN + m0 + tid];
  }
  __syncthreads();

  float acc[16];
  #pragma unroll
  for (int i = 0; i < 16; ++i) acc[i] = 0.f;

  const float* kb = k + (size_t)b * C8 * NN;
  const float* vb = vt + (size_t)b * NN * CC;

  for (int n0 = 0; n0 < NN; n0 += 256) {
    float s[16];
    #pragma unroll
    for (int i = 0; i < 16; ++i) s[i] = 0.f;
    for (int c = 0; c < C8; ++c) {
      float kv = kb[(size_t)c * NN + n0 + tid];
      #pragma unroll
      for (int mi = 0; mi < 16; ++mi)
        s[mi] = fmaf(kv, qs[c][mi], s[mi]);
    }
    __syncthreads();
    #pragma unroll
    for (int mi = 0; mi < 16; ++mi)
      ps[tid][mi] = __expf(s[mi] - rmax_s[mi]) * rsuminv_s[mi];
    __syncthreads();
    for (int nj = 0; nj < 256; ++nj) {
      float vv = vb[(size_t)(n0 + nj) * CC + tid];
      #pragma unroll
      for (int mi = 0; mi < 16; ++mi)
        acc[mi] = fmaf(vv, ps[nj][mi], acc[mi]);
    }
  }

  int y = m0 >> 6;
  int x0 = m0 & 63;
  const float* mb = mask + (size_t)b * 256 * 256;
  size_t ob = ((size_t)b * CC + tid) * NN + m0;
  #pragma unroll
  for (int mi = 0; mi < 16; ++mi) {
    float mv = mb[(4 * y) * 256 + 4 * (x0 + mi)];
    out[ob + mi] = acc[mi] * (1.0f + mv);
  }
}

// ---------------------------------------------------------------------------
extern "C" void kernel_launch(void* const* d_in, const int* in_sizes, int n_in,
                              void* d_out, int out_size, void* d_ws, size_t ws_size,
                              hipStream_t stream)
{
  (void)in_sizes; (void)n_in; (void)out_size; (void)ws_size;
  const float* x      = (const float*)d_in[0];
  const float* mask   = (const float*)d_in[1];
  const float* w_ctx  = (const float*)d_in[2];
  const float* b_ctx  = (const float*)d_in[3];
  const float* w_wide = (const float*)d_in[4];
  const float* b_wide = (const float*)d_in[5];
  const float* w_comb = (const float*)d_in[6];
  const float* b_comb = (const float*)d_in[7];
  const float* w_q    = (const float*)d_in[8];
  const float* b_q    = (const float*)d_in[9];
  const float* w_k    = (const float*)d_in[10];
  const float* b_k    = (const float*)d_in[11];
  const float* w_v    = (const float*)d_in[12];
  const float* b_v    = (const float*)d_in[13];
  float* out = (float*)d_out;

  float* ws = (float*)d_ws;
  const size_t SZ = (size_t)BB * CC * NN;            // 4,194,304 floats

  // phase-aliased workspace layout (float offsets); total 9,576,448 fl = 38.3 MB
  _Float16* localh = (_Float16*)ws;                  // [0, 2097152) fl
  _Float16* wideh  = (_Float16*)(ws + 2097152);      // [2097152, 4194304) fl
  _Float16* xpad   = (_Float16*)(ws + SZ);           // 2,957,312 fl
  _Float16* wb7    = (_Float16*)(ws + 7151616);      // 1,605,632 fl
  _Float16* wb5    = (_Float16*)(ws + 8757248);      // 819,200 fl
  // phase 2 (after convs): multi overwrites xpad, q/k overwrite wb7/wb5
  float* multi  = ws + SZ;                           // [4194304, 8388608)
  float* qbuf   = ws + 8388608;                      // B*32*N
  float* kbuf   = ws + 8912896;
  float* rowmax = ws + 9437184;
  float* rowsum = ws + 9453568;
  // phase 3: v overwrites localh/wideh, v_t overwrites multi
  float* vbuf   = ws;                                // [0, 4194304)
  float* vt     = ws + SZ;                           // [4194304, 8388608)

  pad_kernel<<<BB * 76, 256, 0, stream>>>(x, xpad);
  wcvt_kernel<<<256, 256, 0, stream>>>(w_ctx, wb7, 49);
  wcvt_kernel<<<256, 256, 0, stream>>>(w_wide, wb5, 25);
  conv_mfma_kernel<7, 1><<<256, 512, 0, stream>>>(xpad, wb7, b_ctx, localh);
  conv_mfma_kernel<5, 3><<<256, 512, 0, stream>>>(xpad, wb5, b_wide, wideh);
  combine_kernel<<<16384, 256, 0, stream>>>(localh, wideh, w_comb, b_comb, multi);
  conv1x1_kernel<<<2048, 256, 0, stream>>>(multi, w_q, b_q, qbuf, 32);
  conv1x1_kernel<<<2048, 256, 0, stream>>>(multi, w_k, b_k, kbuf, 32);
  conv1x1_kernel<<<16384, 256, 0, stream>>>(multi, w_v, b_v, vbuf, 256);
  transpose_kernel<<<4096, 256, 0, stream>>>(vbuf, vt);
  softmax_stats_kernel<<<16384, 256, 0, stream>>>(qbuf, kbuf, rowmax, rowsum);
  attn_out_kernel<<<1024, 256, 0, stream>>>(qbuf, kbuf, vt, rowmax, rowsum,
                                            mask, out);
}

// Round 6
// 545.084 us; speedup vs baseline: 9.2348x; 3.0962x over previous
//
#include <hip/hip_runtime.h>
#include <math.h>

#define BB 4
#define CC 256
#define HH 64
#define WW 64
#define NN 4096   // H*W

typedef _Float16 f16x8 __attribute__((ext_vector_type(8)));
typedef float f32x4 __attribute__((ext_vector_type(4)));

// ---------------------------------------------------------------------------
// pad + transpose: xpad[b][pr][pc][ci] = x[b][ci][pr-6][pc-6]  (f16, 0-padded)
// ---------------------------------------------------------------------------
__global__ __launch_bounds__(256) void pad_kernel(
    const float* __restrict__ x, _Float16* __restrict__ xpad)
{
  int blk = blockIdx.x;
  int pr = blk % 76;
  int b  = blk / 76;
  int ci = threadIdx.x;
  int r = pr - 6;
  _Float16* dst = xpad + (((size_t)b*76 + pr)*76)*256 + ci;
  if (r < 0 || r >= HH) {
    for (int pc = 0; pc < 76; ++pc) dst[(size_t)pc*256] = (_Float16)0.f;
  } else {
    const float* src = x + ((size_t)b*CC + ci)*NN + (size_t)r*WW;
    for (int pc = 0; pc < 76; ++pc) {
      int c = pc - 6;
      float v = (c >= 0 && c < WW) ? src[c] : 0.f;
      dst[(size_t)pc*256] = (_Float16)v;
    }
  }
}

// ---------------------------------------------------------------------------
// conv weight convert: dst[t][co][ci] = (f16) src[co][ci][t]
// ---------------------------------------------------------------------------
__global__ __launch_bounds__(256) void wcvt_kernel(
    const float* __restrict__ src, _Float16* __restrict__ dst, int T)
{
  int co = blockIdx.x;
  int ci = threadIdx.x;
  const float* s = src + ((size_t)co*256 + ci)*T;
  for (int t = 0; t < T; ++t)
    dst[(size_t)t*65536 + co*256 + ci] = (_Float16)s[t];
}

// ---------------------------------------------------------------------------
// generic flat f32 -> f16 convert
// ---------------------------------------------------------------------------
__global__ __launch_bounds__(256) void fcvt_kernel(
    const float* __restrict__ src, _Float16* __restrict__ dst, int n)
{
  int i = blockIdx.x * 256 + threadIdx.x;
  if (i < n) dst[i] = (_Float16)src[i];
}

// ---------------------------------------------------------------------------
// implicit-GEMM conv via MFMA 16x16x32 f16. Epilogue: LDS-transpose (reuse xs,
// stride 136 f16 = 272B aligned) and write ctx_t[b][n][512] at c_off.
// ---------------------------------------------------------------------------
template<int KS, int DIL>
__global__ __launch_bounds__(512) void conv_mfma_kernel(
    const _Float16* __restrict__ xpad, const _Float16* __restrict__ wb,
    const float* __restrict__ bias, _Float16* __restrict__ ctx_t, int c_off)
{
  __shared__ __align__(16) char xs[2*76*512];   // staging; reused by epilogue

  int blk = blockIdx.x;
  int ytile = blk & 31;
  int cot = (blk >> 5) & 1;
  int b = blk >> 6;
  int y0 = ytile * 2;
  int tid = threadIdx.x;
  int lane = tid & 63;
  int wv = tid >> 6;
  int wco = wv >> 1;           // 0..3  -> co strip of 32
  int wsp = wv & 1;            // row y0+wsp
  int l15 = lane & 15;
  int lg  = lane >> 4;

  f32x4 acc[2][4];
  #pragma unroll
  for (int m = 0; m < 2; ++m)
    #pragma unroll
    for (int n = 0; n < 4; ++n) acc[m][n] = (f32x4){0.f, 0.f, 0.f, 0.f};

  for (int kh = 0; kh < KS; ++kh) {
    int prow = 6 + y0 + (kh - KS/2) * DIL;
    const uint4* src = (const uint4*)(xpad + (((size_t)b*76 + prow)*76)*256);
    __syncthreads();
    #pragma unroll
    for (int i = 0; i < 10; ++i) {
      int ch = tid + i*512;               // 16B chunks; 2 rows = 4864 chunks
      if (ch < 4864) {
        uint4 v = src[ch];
        int r = ch >> 5, cq = ch & 31;
        *(uint4*)(xs + r*512 + ((cq << 4) ^ ((r & 7) << 4))) = v;
      }
    }
    __syncthreads();
    for (int kw = 0; kw < KS; ++kw) {
      int dx = (kw - KS/2) * DIL;
      int tap = kh*KS + kw;
      const _Float16* wt = wb + ((size_t)tap << 16)
                              + ((size_t)(cot*128 + wco*32 + l15) << 8) + (lg << 3);
      #pragma unroll
      for (int ks = 0; ks < 8; ++ks) {
        f16x8 a0 = *(const f16x8*)(wt + ks*32);
        f16x8 a1 = *(const f16x8*)(wt + 16*256 + ks*32);
        #pragma unroll
        for (int nf = 0; nf < 4; ++nf) {
          int r = wsp*76 + 6 + nf*16 + l15 + dx;
          f16x8 bf = *(const f16x8*)(xs + r*512 + ((ks*64 + (lg << 4)) ^ ((r & 7) << 4)));
          acc[0][nf] = __builtin_amdgcn_mfma_f32_16x16x32_f16(a0, bf, acc[0][nf], 0, 0, 0);
          acc[1][nf] = __builtin_amdgcn_mfma_f32_16x16x32_f16(a1, bf, acc[1][nf], 0, 0, 0);
        }
      }
    }
  }

  // epilogue: LDS transpose tile [128 n][stride 136 co], then coalesced write
  __syncthreads();
  _Float16* ep = (_Float16*)xs;
  #pragma unroll
  for (int m = 0; m < 2; ++m)
    #pragma unroll
    for (int i = 0; i < 4; ++i) {
      int co_l = wco*32 + m*16 + lg*4 + i;
      float bs = bias[cot*128 + co_l];
      #pragma unroll
      for (int nf = 0; nf < 4; ++nf) {
        int n_l = wsp*64 + nf*16 + l15;
        ep[n_l*136 + co_l] = (_Float16)(acc[m][nf][i] + bs);
      }
    }
  __syncthreads();
  const int cbase = c_off + cot*128;
  #pragma unroll
  for (int it = 0; it < 4; ++it) {
    int idx = tid + it*512;
    int n_l = idx >> 4, q = idx & 15;
    f16x8 val = *(const f16x8*)(ep + n_l*136 + q*8);
    *(f16x8*)(ctx_t + ((size_t)b*4096 + (size_t)y0*64 + n_l)*512 + cbase + q*8) = val;
  }
}

// ---------------------------------------------------------------------------
// GEMM producing n-major output: out[n][O] = A[n][K] . Wt[o][K]^T + bias
// grid (n-tiles of 64 over 16384, O/64), 64 threads (1 wave), acc 4x4 frags.
// ---------------------------------------------------------------------------
template<int K, int O, int BIASMODE>
__global__ __launch_bounds__(64) void gemm_nmajor_kernel(
    const _Float16* __restrict__ A, const _Float16* __restrict__ Wt,
    const float* __restrict__ bias0, const float* __restrict__ bias1,
    _Float16* __restrict__ outh)
{
  int nt = blockIdx.x;
  int ot = blockIdx.y;
  int lane = threadIdx.x;
  int l15 = lane & 15, lg = lane >> 4;
  int n0 = nt*64, o0 = ot*64;
  f32x4 acc[4][4] = {};
  for (int k0 = 0; k0 < K; k0 += 32) {
    f16x8 a[4], bfr[4];
    #pragma unroll
    for (int f = 0; f < 4; ++f)
      a[f] = *(const f16x8*)(A + (size_t)(n0 + f*16 + l15)*K + k0 + lg*8);
    #pragma unroll
    for (int f = 0; f < 4; ++f)
      bfr[f] = *(const f16x8*)(Wt + (size_t)(o0 + f*16 + l15)*K + k0 + lg*8);
    #pragma unroll
    for (int i = 0; i < 4; ++i)
      #pragma unroll
      for (int j = 0; j < 4; ++j)
        acc[i][j] = __builtin_amdgcn_mfma_f32_16x16x32_f16(a[i], bfr[j], acc[i][j], 0, 0, 0);
  }
  #pragma unroll
  for (int i = 0; i < 4; ++i)
    #pragma unroll
    for (int j = 0; j < 4; ++j)
      #pragma unroll
      for (int r = 0; r < 4; ++r) {
        int n = n0 + i*16 + lg*4 + r;
        int o = o0 + j*16 + l15;
        float bs = (BIASMODE == 0) ? bias0[o] : (o < 32 ? bias0[o] : bias1[o - 32]);
        outh[(size_t)n*O + o] = (_Float16)(acc[i][j][r] + bs);
      }
}

// ---------------------------------------------------------------------------
// v GEMM: v[b][c][n] = Wv[c][m] . multi_t[n][m]^T + bias  (c-major out)
// ---------------------------------------------------------------------------
__global__ __launch_bounds__(64) void gemm_v_kernel(
    const _Float16* __restrict__ M, const _Float16* __restrict__ Wv,
    const float* __restrict__ bias, _Float16* __restrict__ v)
{
  int nt = blockIdx.x;          // over 16384/64
  int ct = blockIdx.y;          // 0..3
  int lane = threadIdx.x;
  int l15 = lane & 15, lg = lane >> 4;
  int n0 = nt*64, c0 = ct*64;
  f32x4 acc[4][4] = {};
  for (int k0 = 0; k0 < 256; k0 += 32) {
    f16x8 a[4], bfr[4];
    #pragma unroll
    for (int f = 0; f < 4; ++f)
      a[f] = *(const f16x8*)(Wv + (size_t)(c0 + f*16 + l15)*256 + k0 + lg*8);
    #pragma unroll
    for (int f = 0; f < 4; ++f)
      bfr[f] = *(const f16x8*)(M + (size_t)(n0 + f*16 + l15)*256 + k0 + lg*8);
    #pragma unroll
    for (int i = 0; i < 4; ++i)
      #pragma unroll
      for (int j = 0; j < 4; ++j)
        acc[i][j] = __builtin_amdgcn_mfma_f32_16x16x32_f16(a[i], bfr[j], acc[i][j], 0, 0, 0);
  }
  #pragma unroll
  for (int i = 0; i < 4; ++i)
    #pragma unroll
    for (int j = 0; j < 4; ++j)
      #pragma unroll
      for (int r = 0; r < 4; ++r) {
        int c = c0 + i*16 + lg*4 + r;
        int n_abs = n0 + j*16 + l15;
        int b = n_abs >> 12, n = n_abs & 4095;
        v[((size_t)(b*256 + c))*4096 + n] = (_Float16)(acc[i][j][r] + bias[c]);
      }
}

// ---------------------------------------------------------------------------
// attention pass A: per-row running max + sum(exp) over an n-half.
// qkt layout [16384][64] f16: cols 0..31 = q, 32..63 = k.
// grid 512 = b(4) x mt(64) x nh(2), 256 threads (4 waves, 16 m-rows each).
// ---------------------------------------------------------------------------
__global__ __launch_bounds__(256) void attn_stats_kernel(
    const _Float16* __restrict__ qh,
    float* __restrict__ rowmaxP, float* __restrict__ rowsumP)
{
  int blk = blockIdx.x;
  int b = blk >> 7, mt = (blk >> 1) & 63, nh = blk & 1;
  int tid = threadIdx.x, lane = tid & 63, w = tid >> 6;
  int l15 = lane & 15, lg = lane >> 4;
  size_t bN = (size_t)b * 4096;
  int mrow = mt*64 + w*16;
  f16x8 ah = *(const f16x8*)(qh + (bN + mrow + l15)*64 + lg*8);
  float rm[4] = {-3e38f, -3e38f, -3e38f, -3e38f};
  float sm[4] = {0.f, 0.f, 0.f, 0.f};
  for (int n0 = nh*2048; n0 < nh*2048 + 2048; n0 += 16) {
    f16x8 bh = *(const f16x8*)(qh + (bN + n0 + l15)*64 + 32 + lg*8);
    f32x4 s = {};
    s = __builtin_amdgcn_mfma_f32_16x16x32_f16(ah, bh, s, 0, 0, 0);
    #pragma unroll
    for (int i = 0; i < 4; ++i) {
      float nm = fmaxf(rm[i], s[i]);
      sm[i] = sm[i]*__expf(rm[i] - nm) + __expf(s[i] - nm);
      rm[i] = nm;
    }
  }
  #pragma unroll
  for (int off = 1; off <= 8; off <<= 1) {
    #pragma unroll
    for (int i = 0; i < 4; ++i) {
      float rmo = __shfl_xor(rm[i], off);
      float smo = __shfl_xor(sm[i], off);
      float M = fmaxf(rm[i], rmo);
      sm[i] = sm[i]*__expf(rm[i] - M) + smo*__expf(rmo - M);
      rm[i] = M;
    }
  }
  if (l15 == 0) {
    #pragma unroll
    for (int i = 0; i < 4; ++i) {
      size_t idx = (size_t)nh*16384 + bN + mrow + lg*4 + i;
      rowmaxP[idx] = rm[i];
      rowsumP[idx] = sm[i];
    }
  }
}

// ---------------------------------------------------------------------------
// attention pass B: O[m64][c256] = P . V^T with P recomputed per 32-n chunk.
// grid 256 = b(4) x mt(64), 512 threads (8 waves).
// vs/pl strides = 40 f16 (80B): 16B-aligned rows for ds_read_b128.
// ---------------------------------------------------------------------------
__global__ __launch_bounds__(512) void attn_out_kernel(
    const _Float16* __restrict__ qh, const _Float16* __restrict__ v,
    const float* __restrict__ rowmaxP, const float* __restrict__ rowsumP,
    const float* __restrict__ mask, float* __restrict__ out)
{
  __shared__ union U {
    struct { __align__(16) _Float16 vs[256*40]; __align__(16) _Float16 pl[64*40]; } s;
    float epi[256*68];
  } u;
  int blk = blockIdx.x;
  int b = blk >> 6, mt = blk & 63;
  int tid = threadIdx.x, lane = tid & 63, w = tid >> 6;
  int l15 = lane & 15, lg = lane >> 4;
  size_t bN = (size_t)b * 4096;
  int m0 = mt*64;

  // QK role
  int mf = w >> 1, nf2 = w & 1;
  f16x8 ah = *(const f16x8*)(qh + (bN + m0 + mf*16 + l15)*64 + lg*8);
  float rm[4], rsi[4];
  #pragma unroll
  for (int i = 0; i < 4; ++i) {
    size_t m = bN + m0 + mf*16 + lg*4 + i;
    float r0 = rowmaxP[m], r1 = rowmaxP[16384 + m];
    float s0 = rowsumP[m], s1 = rowsumP[16384 + m];
    float M = fmaxf(r0, r1);
    rm[i] = M;
    rsi[i] = 1.0f / (s0*__expf(r0 - M) + s1*__expf(r1 - M));
  }
  // PV role
  int mh = w >> 2, cw = (w & 3)*64;
  f32x4 acc[2][4] = {};
  const _Float16* vb = v + (size_t)b*256*4096;

  for (int n0 = 0; n0 < 4096; n0 += 32) {
    // stage v tile [256 c][32 n] (stride 40 f16)
    #pragma unroll
    for (int it = 0; it < 2; ++it) {
      int idx = tid + it*512;
      int c = idx >> 2, q = idx & 3;
      *(f16x8*)(u.s.vs + c*40 + q*8) = *(const f16x8*)(vb + (size_t)c*4096 + n0 + q*8);
    }
    // QK + exp -> P (f16) in LDS
    {
      f16x8 bh = *(const f16x8*)(qh + (bN + n0 + nf2*16 + l15)*64 + 32 + lg*8);
      f32x4 s = {};
      s = __builtin_amdgcn_mfma_f32_16x16x32_f16(ah, bh, s, 0, 0, 0);
      #pragma unroll
      for (int i = 0; i < 4; ++i) {
        float p = __expf(s[i] - rm[i]) * rsi[i];
        u.s.pl[(mf*16 + lg*4 + i)*40 + nf2*16 + l15] = (_Float16)p;
      }
    }
    __syncthreads();
    // PV
    {
      f16x8 pa[2], pb[4];
      #pragma unroll
      for (int af = 0; af < 2; ++af)
        pa[af] = *(const f16x8*)(u.s.pl + (mh*32 + af*16 + l15)*40 + lg*8);
      #pragma unroll
      for (int bf = 0; bf < 4; ++bf)
        pb[bf] = *(const f16x8*)(u.s.vs + (cw + bf*16 + l15)*40 + lg*8);
      #pragma unroll
      for (int af = 0; af < 2; ++af)
        #pragma unroll
        for (int bf = 0; bf < 4; ++bf)
          acc[af][bf] = __builtin_amdgcn_mfma_f32_16x16x32_f16(pa[af], pb[bf], acc[af][bf], 0, 0, 0);
    }
    __syncthreads();
  }

  // epilogue: transpose via LDS, apply (1+mask), write out[b][c][m]
  #pragma unroll
  for (int af = 0; af < 2; ++af)
    #pragma unroll
    for (int bf = 0; bf < 4; ++bf)
      #pragma unroll
      for (int r = 0; r < 4; ++r) {
        int c = cw + bf*16 + l15;
        int ml = mh*32 + af*16 + lg*4 + r;
        u.epi[c*68 + ml] = acc[af][bf][r];
      }
  __syncthreads();
  const float* mb = mask + (size_t)b*65536 + (size_t)(mt*4)*256;
  #pragma unroll
  for (int it = 0; it < 8; ++it) {
    int idx = tid + it*512;
    int c = idx >> 4, q = idx & 15;
    f32x4 val = *(const f32x4*)(u.epi + c*68 + q*4);
    f32x4 o4;
    #pragma unroll
    for (int jj = 0; jj < 4; ++jj) {
      int xcol = q*4 + jj;
      o4[jj] = val[jj] * (1.0f + mb[xcol*4]);
    }
    *(f32x4*)(out + ((size_t)b*256 + c)*4096 + m0 + q*4) = o4;
  }
}

// ---------------------------------------------------------------------------
extern "C" void kernel_launch(void* const* d_in, const int* in_sizes, int n_in,
                              void* d_out, int out_size, void* d_ws, size_t ws_size,
                              hipStream_t stream)
{
  (void)in_sizes; (void)n_in; (void)out_size; (void)ws_size;
  const float* x      = (const float*)d_in[0];
  const float* mask   = (const float*)d_in[1];
  const float* w_ctx  = (const float*)d_in[2];
  const float* b_ctx  = (const float*)d_in[3];
  const float* w_wide = (const float*)d_in[4];
  const float* b_wide = (const float*)d_in[5];
  const float* w_comb = (const float*)d_in[6];
  const float* b_comb = (const float*)d_in[7];
  const float* w_q    = (const float*)d_in[8];
  const float* b_q    = (const float*)d_in[9];
  const float* w_k    = (const float*)d_in[10];
  const float* b_k    = (const float*)d_in[11];
  const float* w_v    = (const float*)d_in[12];
  const float* b_v    = (const float*)d_in[13];
  float* out = (float*)d_out;

  float* ws = (float*)d_ws;
  // --- CORRECTED phase-aliased layout (float offsets). Total 9,682,944 fl
  //     = 38.7 MB (< 54.7 MB proven in round 1).
  // Phase 1 (pre/conv):
  //   xpad  [0,         2,957,312)   4*76*76*256 f16 = 5,914,624 f16
  //   wb7   [2,957,312, 4,562,944)   49*65536 f16
  //   wb5   [4,562,944, 5,382,144)   25*65536 f16
  //   ctx_t [5,382,144, 9,576,448)   16384*512 f16
  //   wcombH[9,576,448, 9,641,984)   256*512 f16
  //   wqkH  [9,641,984, 9,650,176)   64*256 f16
  //   wvH   [9,650,176, 9,682,944)   256*256 f16
  _Float16* xpad    = (_Float16*)(ws);
  _Float16* wb7     = (_Float16*)(ws + 2957312);
  _Float16* wb5     = (_Float16*)(ws + 4562944);
  _Float16* ctx_t   = (_Float16*)(ws + 5382144);
  _Float16* wcombH  = (_Float16*)(ws + 9576448);
  _Float16* wqkH    = (_Float16*)(ws + 9641984);
  _Float16* wvH     = (_Float16*)(ws + 9650176);
  // Phase 2 (after convs; xpad/wb7/wb5 dead, ctx_t live):
  //   multi_t [0,         2,097,152)  16384*256 f16
  //   qkt_h   [2,097,152, 2,621,440)  16384*64 f16
  //   rowmaxP [2,621,440, 2,654,208)  2*16384 f32
  //   rowsumP [2,654,208, 2,686,976)  2*16384 f32
  _Float16* multi_t = (_Float16*)(ws);
  _Float16* qkt_h   = (_Float16*)(ws + 2097152);
  float*    rowmaxP = ws + 2621440;
  float*    rowsumP = ws + 2654208;
  // Phase 3 (after combine; ctx_t dead):
  //   vbuf [5,382,144, 7,479,296)  4*256*4096 f16
  _Float16* vbuf    = (_Float16*)(ws + 5382144);

  pad_kernel<<<BB*76, 256, 0, stream>>>(x, xpad);
  wcvt_kernel<<<256, 256, 0, stream>>>(w_ctx, wb7, 49);
  wcvt_kernel<<<256, 256, 0, stream>>>(w_wide, wb5, 25);
  fcvt_kernel<<<512, 256, 0, stream>>>(w_comb, wcombH, 131072);
  fcvt_kernel<<<32, 256, 0, stream>>>(w_q, wqkH, 8192);
  fcvt_kernel<<<32, 256, 0, stream>>>(w_k, wqkH + 8192, 8192);
  fcvt_kernel<<<256, 256, 0, stream>>>(w_v, wvH, 65536);

  conv_mfma_kernel<7, 1><<<256, 512, 0, stream>>>(xpad, wb7, b_ctx, ctx_t, 0);
  conv_mfma_kernel<5, 3><<<256, 512, 0, stream>>>(xpad, wb5, b_wide, ctx_t, 256);

  gemm_nmajor_kernel<512, 256, 0><<<dim3(256, 4), 64, 0, stream>>>(
      ctx_t, wcombH, b_comb, nullptr, multi_t);
  gemm_nmajor_kernel<256, 64, 1><<<dim3(256, 1), 64, 0, stream>>>(
      multi_t, wqkH, b_q, b_k, qkt_h);
  gemm_v_kernel<<<dim3(256, 4), 64, 0, stream>>>(multi_t, wvH, b_v, vbuf);

  attn_stats_kernel<<<512, 256, 0, stream>>>(qkt_h, rowmaxP, rowsumP);
  attn_out_kernel<<<256, 512, 0, stream>>>(qkt_h, vbuf, rowmaxP, rowsumP,
                                           mask, out);
}